// Round 14
// baseline (42.021 us; speedup 1.0000x reference)
//
#include <hip/hip_runtime.h>

#define B_SZ 1024
#define F_SZ 512
#define NK   50
#define KD   5
#define C_SZ 250              // NK*KD
#define OUTW 562              // F_SZ + NK
#define PLANE (C_SZ * B_SZ)   // SoA M plane: [col c=k*5+d][row], 256000 floats
#define NT   16               // 16 row-tiles of 64
#define TILE 64
#define NPAIRS 136            // NT*(NT+1)/2 unordered tile pairs
#define PBLK  34              // tile pairs per block (4 waves x 34 blocks = 136)
#define PART_ELEMS (NK * NT * B_SZ)   // 819200 floats
#define LOG2E 1.44269504088896340736f

// ---------------------------------------------------------------------------
// K1: fused GEMM + copy (round-9 version — measured best). grid 384 x 256.
//  blocks [0,256):   M = x@T scaled by log2e, SoA planes ws2[ks][c][row].
//                    rt = blk&127 (8 rows), ks = blk>>7 (256 f each).
//                    64 MB total T re-reads (L2/L3); x block-uniform -> s_load.
//  blocks [256,384): copy x rows into out (float2), 8 rows/block.
// ---------------------------------------------------------------------------
__global__ __launch_bounds__(256) void gemm_copy_kernel(const float* __restrict__ x,
                                                        const float* __restrict__ T,
                                                        float* __restrict__ ws2,
                                                        float* __restrict__ out,
                                                        int zero_feat) {
    const int t = threadIdx.x;

    if (blockIdx.x >= 256) {                 // ---- copy path
        const int b = blockIdx.x - 256;      // 0..127
#pragma unroll
        for (int r = 0; r < 8; ++r) {
            const int row = b * 8 + r;
            const float2* src = (const float2*)(x + (size_t)row * F_SZ);
            float2* dst = (float2*)(out + (size_t)row * OUTW);
            dst[t] = src[t];
            if (zero_feat && t < NK) out[(size_t)row * OUTW + F_SZ + t] = 0.0f;
        }
        return;
    }

    // ---- gemm path
    const int rt = blockIdx.x & 127;         // 8-row tile
    const int ks = blockIdx.x >> 7;          // k-split (0,1)
    if (t >= C_SZ) return;                   // no __syncthreads in this path
    const int r0 = rt * 8;
    const int f0 = ks * 256;

    float acc[8] = {0.f, 0.f, 0.f, 0.f, 0.f, 0.f, 0.f, 0.f};
    const float* xp = x + (size_t)r0 * F_SZ + f0;     // block-uniform base
    const float* Tp = T + (size_t)f0 * C_SZ + t;

#pragma unroll 8
    for (int f = 0; f < 256; ++f) {
        const float tv = Tp[(size_t)f * C_SZ];
#pragma unroll
        for (int r = 0; r < 8; ++r)
            acc[r] += xp[r * F_SZ + f] * tv;          // uniform -> s_load
    }

    float* dst = ws2 + ((size_t)(ks * C_SZ + t)) * B_SZ + r0;   // 32B aligned
    float4 lo = make_float4(acc[0] * LOG2E, acc[1] * LOG2E,
                            acc[2] * LOG2E, acc[3] * LOG2E);
    float4 hi = make_float4(acc[4] * LOG2E, acc[5] * LOG2E,
                            acc[6] * LOG2E, acc[7] * LOG2E);
    ((float4*)dst)[0] = lo;
    ((float4*)dst)[1] = hi;
}

// ---------------------------------------------------------------------------
// wave_ror1: full-wave rotate by one lane (DPP ctrl 0x13C, gfx9 family —
// same encodings as round-12's row_bcast 0x142/0x143 which ran correctly).
// All masks full; pure VALU-pipe lane permute, no LDS.
// ---------------------------------------------------------------------------
__device__ __forceinline__ float wave_ror1(float v) {
    return __int_as_float(__builtin_amdgcn_update_dpp(
        0, __float_as_int(v), 0x13C, 0xf, 0xf, false));
}

// ---------------------------------------------------------------------------
// K2: symmetric pairwise features via ROTATION — zero LDS, zero barriers,
// zero wasted lanes (round-12 lesson: DPP butterflies waste 63/64 lanes;
// round-13 lesson: et-in-LDS makes pair LDS-pipe-bound at ~10us).
// grid 1700 = 50 k x 34 blocks; 256 threads = 4 waves; each wave owns ONE
// (ti,tj) tile pair and computes the full 64x64 e-block in 64 rotation steps:
//   step s: lane l holds mj/vcol slot for column f_s(l); computes
//   e(i=l, j=f_s(l)); acci += e (row sum, fixed frame); vcol += e (col sum,
//   rotating frame — travels WITH the j-data, so slot j collects all i).
//   Then mj[0..4] and vcol rotate one lane. After 64 steps both are home:
//   vcol[l] = colsum(bj+l). Per step: 5 sub + 4 add + exp2 + 2 acc + 6 DPP.
// Partials part[k][src_tile][row], each cell written by exactly one wave
// (acci -> src=tj at rows of ti; vcol -> src=ti at rows of tj; diag: acci
// only). NO atomics / fences on the fast path.
// ---------------------------------------------------------------------------
template <bool ATOMIC>
__global__ __launch_bounds__(256) void pair_kernel(const float* __restrict__ ws2,
                                                   float* __restrict__ part,
                                                   float* __restrict__ out) {
    const int bid  = blockIdx.x;
    const int k    = bid / PBLK;
    const int wv   = __builtin_amdgcn_readfirstlane(threadIdx.x >> 6);
    const int lane = threadIdx.x & 63;

    // decode pair index -> (ti, tj); scalar-uniform short loop
    int p = (bid - k * PBLK) * 4 + wv;       // 0..135
    int ti = 0;
    while (p >= NT - ti) { p -= NT - ti; ++ti; }
    const int tj = ti + p;
    const int bi = ti * TILE;
    const int bj = tj * TILE;
    const bool diag = (ti == tj);

    const float* pa = ws2 + (size_t)k * (KD * B_SZ);  // plane 0, cols k*5..
    const float* pb = pa + (size_t)PLANE;             // plane 1

    // register-resident tiles (sum the two k-split planes at load)
    float mi[KD], mj[KD];
#pragma unroll
    for (int d = 0; d < KD; ++d) {
        mi[d] = pa[d * B_SZ + bi + lane] + pb[d * B_SZ + bi + lane];
        mj[d] = pa[d * B_SZ + bj + lane] + pb[d * B_SZ + bj + lane];
    }

    float acci = 0.0f;   // row sums (fixed frame): i = bi+lane over all j in tj
    float vcol = 0.0f;   // col sums (rotating frame): travels with mj

#pragma unroll 16
    for (int s = 0; s < TILE; ++s) {
        const float sum = __builtin_fabsf(mi[0] - mj[0])
                        + __builtin_fabsf(mi[1] - mj[1])
                        + __builtin_fabsf(mi[2] - mj[2])
                        + __builtin_fabsf(mi[3] - mj[3])
                        + __builtin_fabsf(mi[4] - mj[4]);
        const float e = __builtin_amdgcn_exp2f(-sum);
        acci += e;
        vcol += e;
        // rotate j-frame (data + its accumulator) one lane
        mj[0] = wave_ror1(mj[0]);
        mj[1] = wave_ror1(mj[1]);
        mj[2] = wave_ror1(mj[2]);
        mj[3] = wave_ror1(mj[3]);
        mj[4] = wave_ror1(mj[4]);
        vcol  = wave_ror1(vcol);
    }
    // 64 rotations -> home: vcol[lane] = sum_i e(i, bj+lane)

    if (ATOMIC) {
        atomicAdd(&out[(size_t)(bi + lane) * OUTW + F_SZ + k], acci);
        if (!diag)
            atomicAdd(&out[(size_t)(bj + lane) * OUTW + F_SZ + k], vcol);
    } else {
        part[(size_t)(k * NT + tj) * B_SZ + bi + lane] = acci;
        if (!diag)
            part[(size_t)(k * NT + ti) * B_SZ + bj + lane] = vcol;
    }
}

// ---------------------------------------------------------------------------
// K3: fold the 16 tile-source partials into out. grid 200 x 256.
// Reads coalesced (lanes contiguous in row); L2-resident.
// ---------------------------------------------------------------------------
__global__ __launch_bounds__(256) void reduce_kernel(const float* __restrict__ part,
                                                     float* __restrict__ out) {
    const int k = blockIdx.x >> 2;
    const int i = ((blockIdx.x & 3) << 8) | threadIdx.x;
    float s = 0.0f;
#pragma unroll
    for (int sp = 0; sp < NT; ++sp)
        s += part[((size_t)(k * NT + sp)) * B_SZ + i];
    out[(size_t)i * OUTW + F_SZ + k] = s;
}

// ---------------------------------------------------------------------------
extern "C" void kernel_launch(void* const* d_in, const int* in_sizes, int n_in,
                              void* d_out, int out_size, void* d_ws, size_t ws_size,
                              hipStream_t stream) {
    const float* x = (const float*)d_in[0];   // [1024, 512]
    const float* T = (const float*)d_in[1];   // [512, 250]
    float* out = (float*)d_out;               // [1024, 562]
    float* ws2 = (float*)d_ws;                // 2 SoA planes [250][1024]
    float* part = ws2 + 2 * (size_t)PLANE;    // [50][16][1024]

    const size_t need = (size_t)(2 * PLANE + PART_ELEMS) * 4;   // 5.3 MB
    const int fast = (ws_size >= need);

    gemm_copy_kernel<<<384, 256, 0, stream>>>(x, T, ws2, out, fast ? 0 : 1);

    if (fast) {
        pair_kernel<false><<<NK * PBLK, 256, 0, stream>>>(ws2, part, out);
        reduce_kernel<<<200, 256, 0, stream>>>(part, out);
    } else {
        pair_kernel<true><<<NK * PBLK, 256, 0, stream>>>(ws2, nullptr, out);
    }
}